// Round 6
// baseline (12.766 us; speedup 1.0000x reference)
//
#include <hip/hip_runtime.h>
#include <hip/hip_bf16.h>
#include <math.h>

// out[b] = bias + sum_{i,j} W[i,j] * leaky(cf[b,i]*pf[b,j]),  leaky(z)=0.55z+0.45|z|
// Contract over j (no W transpose):
//   Gp[b,i] = sum_j pf[b,j] W[i,j],  Hp[b,i] = sum_j |pf[b,j]| W[i,j]
//   out[b]  = bias + sum_i ( 0.55 cf[b,i] Gp[b,i] + 0.45 |cf[b,i]| Hp[b,i] )
// Round-6 vs round-5: same algorithm/traffic, but 512-thread blocks (8 waves,
// each wave 32 b-rows) -> 4 waves/SIMD instead of 2; per-thread stage work
// halved; epilogue cf loads hoisted before the barrier to overlap staging.
// Partials to ws[b][block] (plain stores), wave-per-row reduce adds bias.

constexpr int B = 256, D = 1024;
constexpr int BN = 32;          // i-tile (MFMA N dim)
constexpr int JC = 64;          // j-chunk (contraction split)
constexpr int NT = D / BN;      // 32
constexpr int KC = D / JC;      // 16
constexpr int NBLK = NT * KC;   // 512 partial sets
constexpr int LDP = 72;         // padded LDS row (bf16 elems)

typedef __attribute__((ext_vector_type(8))) short bf16x8;
typedef __attribute__((ext_vector_type(4))) short bf16x4;
typedef __attribute__((ext_vector_type(4))) float f32x4;
typedef __attribute__((ext_vector_type(4))) int   int32x4;

__device__ __forceinline__ ushort f2bf(float x) {
    __hip_bfloat16 h = __float2bfloat16(x);
    return *reinterpret_cast<ushort*>(&h);
}

__device__ __forceinline__ bf16x8 cvt8(float4 lo, float4 hi) {
    bf16x8 v;
    v[0] = (short)f2bf(lo.x); v[1] = (short)f2bf(lo.y);
    v[2] = (short)f2bf(lo.z); v[3] = (short)f2bf(lo.w);
    v[4] = (short)f2bf(hi.x); v[5] = (short)f2bf(hi.y);
    v[6] = (short)f2bf(hi.z); v[7] = (short)f2bf(hi.w);
    return v;
}

__global__ __launch_bounds__(512) void opl_main(
    const float* __restrict__ cf, const float* __restrict__ pf,
    const float* __restrict__ W, float* __restrict__ ws)
{
    __shared__ ushort sP[B][LDP];   // pf tile  [256][72] bf16 = 36.0 KB
    __shared__ ushort sW[BN][LDP];  // W  tile  [ 32][72] bf16 =  4.5 KB

    const int nt = blockIdx.x & (NT - 1);
    const int kc = blockIdx.x >> 5;
    const int ibase = nt * BN, jbase = kc * JC;
    const int t = threadIdx.x;

    // ---- stage W: 16 threads/row (256B runs), 4 floats each ----
    {
        const int r = t >> 4, c = (t & 15) * 4;
        const float4 v = *reinterpret_cast<const float4*>(&W[(size_t)(ibase + r) * D + jbase + c]);
        bf16x4 o;
        o[0] = (short)f2bf(v.x); o[1] = (short)f2bf(v.y);
        o[2] = (short)f2bf(v.z); o[3] = (short)f2bf(v.w);
        *reinterpret_cast<bf16x4*>(&sW[r][c]) = o;
    }
    // ---- stage pf: 8 threads/row (256B runs), 8 floats each, 4 passes ----
    #pragma unroll
    for (int p = 0; p < 4; ++p) {
        const int r = p * 64 + (t >> 3), c = (t & 7) * 8;
        const float* src = &pf[(size_t)r * D + jbase + c];
        const float4 lo = *reinterpret_cast<const float4*>(src);
        const float4 hi = *reinterpret_cast<const float4*>(src + 4);
        *reinterpret_cast<bf16x8*>(&sP[r][c]) = cvt8(lo, hi);
    }

    // ---- hoisted epilogue cf loads (independent of LDS; overlap staging) ----
    const int lane = t & 63;
    const int wid = t >> 6;
    const int mwave = wid * 32;     // 8 waves x 32 b-rows = 256 = B
    const int r16 = lane & 15;      // m/n index within fragment
    const int g = lane >> 4;        // k-block for A/B; row-group for C/D

    float cfv[2][2][4];
    #pragma unroll
    for (int mf = 0; mf < 2; ++mf)
        #pragma unroll
        for (int nf = 0; nf < 2; ++nf)
            #pragma unroll
            for (int r = 0; r < 4; ++r)
                cfv[mf][nf][r] = cf[(size_t)(mwave + mf * 16 + g * 4 + r) * D + ibase + nf * 16 + r16];

    __syncthreads();

    // ---- MFMA: wave = 32 b-rows x 32 i-cols, K = JC ----
    f32x4 accG[2][2] = {};
    f32x4 accH[2][2] = {};

    #pragma unroll
    for (int ks = 0; ks < JC / 32; ++ks) {
        const int c0 = ks * 32 + g * 8;
        bf16x8 a[2], b[2];
        #pragma unroll
        for (int mf = 0; mf < 2; ++mf)
            a[mf] = *reinterpret_cast<const bf16x8*>(&sP[mwave + mf * 16 + r16][c0]);
        #pragma unroll
        for (int nf = 0; nf < 2; ++nf)
            b[nf] = *reinterpret_cast<const bf16x8*>(&sW[nf * 16 + r16][c0]);
        #pragma unroll
        for (int mf = 0; mf < 2; ++mf) {
            int32x4 ai = __builtin_bit_cast(int32x4, a[mf]);
            ai &= 0x7fff7fff;       // |pf| exactly: clear bf16 sign bits
            const bf16x8 aa = __builtin_bit_cast(bf16x8, ai);
            #pragma unroll
            for (int nf = 0; nf < 2; ++nf) {
                accG[mf][nf] = __builtin_amdgcn_mfma_f32_16x16x32_bf16(a[mf], b[nf], accG[mf][nf], 0, 0, 0);
                accH[mf][nf] = __builtin_amdgcn_mfma_f32_16x16x32_bf16(aa,    b[nf], accH[mf][nf], 0, 0, 0);
            }
        }
    }

    // ---- epilogue: C/D col=lane&15 -> i, row=(lane>>4)*4+r -> b ----
    float s[2][4];
    #pragma unroll
    for (int mf = 0; mf < 2; ++mf)
        #pragma unroll
        for (int r = 0; r < 4; ++r) s[mf][r] = 0.f;

    #pragma unroll
    for (int mf = 0; mf < 2; ++mf) {
        #pragma unroll
        for (int nf = 0; nf < 2; ++nf) {
            #pragma unroll
            for (int r = 0; r < 4; ++r) {
                const float c = cfv[mf][nf][r];
                s[mf][r] = fmaf(0.55f * c, accG[mf][nf][r],
                           fmaf(0.45f * fabsf(c), accH[mf][nf][r], s[mf][r]));
            }
        }
    }
    #pragma unroll
    for (int mf = 0; mf < 2; ++mf) {
        #pragma unroll
        for (int r = 0; r < 4; ++r) {
            float v = s[mf][r];
            v += __shfl_xor(v, 1);
            v += __shfl_xor(v, 2);
            v += __shfl_xor(v, 4);
            v += __shfl_xor(v, 8);
            s[mf][r] = v;
        }
    }
    // plain stores of per-block partials: ws[b][block]; no atomics
    if (r16 == 0) {
        #pragma unroll
        for (int mf = 0; mf < 2; ++mf)
            #pragma unroll
            for (int r = 0; r < 4; ++r)
                ws[(size_t)(mwave + mf * 16 + g * 4 + r) * NBLK + blockIdx.x] = s[mf][r];
    }
}

// one wave per batch row: sum 512 contiguous partials + bias
__global__ __launch_bounds__(256) void opl_reduce(
    const float* __restrict__ ws, const float* __restrict__ bias,
    float* __restrict__ out)
{
    const int wid = threadIdx.x >> 6, lane = threadIdx.x & 63;
    const int b = blockIdx.x * 4 + wid;
    const float* p = ws + (size_t)b * NBLK;
    float s = 0.f;
    #pragma unroll
    for (int k = 0; k < NBLK / 64; ++k) s += p[lane + k * 64];
    #pragma unroll
    for (int off = 1; off < 64; off <<= 1) s += __shfl_xor(s, off);
    if (lane == 0) out[b] = s + bias[0];
}

extern "C" void kernel_launch(void* const* d_in, const int* in_sizes, int n_in,
                              void* d_out, int out_size, void* d_ws, size_t ws_size,
                              hipStream_t stream) {
    const float* cf   = (const float*)d_in[0];
    const float* pf   = (const float*)d_in[1];
    const float* W    = (const float*)d_in[2];
    const float* bias = (const float*)d_in[3];
    float* out = (float*)d_out;
    float* ws  = (float*)d_ws;   // B * NBLK * 4 = 512 KB, fully rewritten each call

    opl_main<<<NT * KC, 512, 0, stream>>>(cf, pf, W, ws);
    opl_reduce<<<B / 4, 256, 0, stream>>>(ws, bias, out);
}